// Round 1
// baseline (320.685 us; speedup 1.0000x reference)
//
#include <hip/hip_runtime.h>
#include <hip/hip_bf16.h>

typedef float  float4v __attribute__((ext_vector_type(4)));
typedef short  short8v __attribute__((ext_vector_type(8)));
typedef short  short4v __attribute__((ext_vector_type(4)));
typedef __bf16 bf16x8  __attribute__((ext_vector_type(8)));
typedef float  f32x4   __attribute__((ext_vector_type(4)));

constexpr int NB = 512, T = 64, DIN = 1024, DOUT = 1024;

// ---- workspace layout (bf16-DMA path) ----
constexpr size_t ABF_BYTES = (size_t)NB * T * DIN * 2;   // 67,108,864
constexpr size_t WN_BYTES  = (size_t)DOUT * DIN * 2;     // 2,097,152
constexpr size_t WS_BF16   = ABF_BYTES + WN_BYTES;       // ~69 MB

__device__ __forceinline__ short f2bf_rne(float x) {
    return __builtin_bit_cast(short, __float2bfloat16(x));
}
__device__ __forceinline__ short f2bf_trunc(float x) {   // exact for {0,1}
    return (short)(__builtin_bit_cast(unsigned int, x) >> 16);
}
__device__ __forceinline__ void load_lds_16B(const void* g, void* l) {
    __builtin_amdgcn_global_load_lds(
        (const __attribute__((address_space(1))) unsigned int*)g,
        (__attribute__((address_space(3))) unsigned int*)l, 16, 0, 0);
}

// ---- fused prepass: A fp32{0,1} -> bf16 (trunc, exact) AND Wn = bf16(W*ratio)
constexpr int PREP_A_BLOCKS = NB * T * DIN / 8 / 256;    // 16384
constexpr int PREP_W_BLOCKS = DOUT * DIN / 4 / 256;      // 1024

__global__ void __launch_bounds__(256)
prep_fused(const float* __restrict__ A, short* __restrict__ Abf,
           const float* __restrict__ W, const float* __restrict__ gamma,
           const float* __restrict__ rvar, short* __restrict__ Wn) {
    const int b = blockIdx.x;
    if (b < PREP_A_BLOCKS) {
        int idx = b * 256 + threadIdx.x;                 // 8-elem group
        const float4v* p = (const float4v*)A + (size_t)idx * 2;
        float4v v0 = __builtin_nontemporal_load(p);
        float4v v1 = __builtin_nontemporal_load(p + 1);
        short8v s;
        #pragma unroll
        for (int j = 0; j < 4; j++) {
            s[j]     = f2bf_trunc(v0[j]);
            s[j + 4] = f2bf_trunc(v1[j]);
        }
        *((short8v*)Abf + idx) = s;                      // cached: re-read soon
    } else {
        int idx = (b - PREP_A_BLOCKS) * 256 + threadIdx.x;  // float4 group
        int o = idx >> 8;
        float r = gamma[o] / sqrtf(rvar[o]);
        float4v w = ((const float4v*)W)[idx];
        short4v s;
        #pragma unroll
        for (int j = 0; j < 4; j++) s[j] = f2bf_rne(w[j] * r);
        ((short4v*)Wn)[idx] = s;
    }
}

// standalone fold (used by the ws-small fallback path only)
__global__ void __launch_bounds__(256)
fold_w_kernel(const float* __restrict__ W, const float* __restrict__ gamma,
              const float* __restrict__ rvar, short* __restrict__ Wn) {
    int idx = blockIdx.x * 256 + threadIdx.x;
    int o = idx >> 8;
    float r = gamma[o] / sqrtf(rvar[o]);
    float4v w = ((const float4v*)W)[idx];
    short4v s;
    #pragma unroll
    for (int j = 0; j < 4; j++) s[j] = f2bf_rne(w[j] * r);
    ((short4v*)Wn)[idx] = s;
}

// =====================================================================
// main: 256x256 tile, BK=32, TRIPLE-buffered LDS, counted vmcnt(4),
// one barrier per K-step (race-free depth-2 pipeline), + IF scan.
//
// Pipeline invariant (per wave, 4 global_load_lds per STAGE, FIFO vmcnt):
//   step t issues stage(t+2)->buf[(t+2)%3]; end-of-step vmcnt(4) retires
//   everything except the 4 newest loads => stage(t+1) fully landed;
//   barrier aligns waves => buf[(t+1)%3] safe to read at t+1.
//   WAR: stage(t+2) overwrites buf[(t-1)%3], whose readers all passed the
//   barrier at end of step t-1. No sub-step hazards exist.
// =====================================================================
constexpr int BM2 = 256, BN2 = 256, BK2 = 32;
constexpr int NSTEP2 = DIN / BK2;                 // 32
constexpr int BUFB   = (BM2 + BN2) * BK2 * 2;     // 32768 B per buffer
constexpr int BREG   = BM2 * BK2 * 2;             // 16384: B region offset

__global__ void __launch_bounds__(512, 2)
snn_gemm_if_256(const short* __restrict__ Abf,  // (N*T, DIN) bf16 {0,1}
                const short* __restrict__ Wn,   // (DOUT, DIN) bf16, BN-folded
                const float* __restrict__ bias, const float* __restrict__ gamma,
                const float* __restrict__ beta, const float* __restrict__ rmean,
                const float* __restrict__ rvar, float* __restrict__ out) {
    __shared__ __align__(16) char sm[3 * BUFB];   // 96 KB staging; potS reuse
    __shared__ float bstepS[BN2];

    const int tid = threadIdx.x;
    const int oB  = blockIdx.x * BN2;             // 4 col-blocks share A panel
    const int bs  = blockIdx.y;                   // 4 samples per block

    if (tid < BN2) {
        int o = oB + tid;
        float r = gamma[o] / sqrtf(rvar[o]);
        bstepS[tid] = ((bias[o] - rmean[o]) * r + beta[o]) * (1.0f / 64.0f);
    }

    const int lane = tid & 63;
    const int wv   = tid >> 6;
    const int wr   = wv >> 2;                     // M-half (0..1)
    const int wc   = wv & 3;                      // N-quarter (0..3)
    const int l15  = lane & 15;
    const int quad = lane >> 4;

    // fragment LDS byte-offsets.  BK=32 -> 4 chunks/row; swizzle
    // chunk ^= (row>>1)&3 gives 2-way (free) bank aliasing per 16-lane phase.
    int aOff[8], bOff[4];
    #pragma unroll
    for (int mi = 0; mi < 8; mi++) {
        int r = wr * 128 + mi * 16 + l15;
        aOff[mi] = (r * 4 + (quad ^ ((r >> 1) & 3))) * 16;
    }
    #pragma unroll
    for (int ni = 0; ni < 4; ni++) {
        int r = wc * 64 + ni * 16 + l15;
        bOff[ni] = BREG + (r * 4 + (quad ^ ((r >> 1) & 3))) * 16;
    }

    f32x4 acc[8][4] = {};

    // staging: slot s (linear dest, wave-uniform base + lane*16) pulls global
    // chunk (s&3)^((row>>1)&3) of row s>>2 -- the inverse of the read swizzle.
    const int s0 = tid, s1 = 512 + tid;
    const int r0 = s0 >> 2, r1 = s1 >> 2;
    const int c0 = (s0 & 3) ^ ((r0 >> 1) & 3);
    const int c1 = (s1 & 3) ^ ((r1 >> 1) & 3);
    const short* gA0 = Abf + (size_t)(bs * BM2 + r0) * DIN + c0 * 8;
    const short* gA1 = Abf + (size_t)(bs * BM2 + r1) * DIN + c1 * 8;
    const short* gB0 = Wn + (size_t)(oB + r0) * DIN + c0 * 8;
    const short* gB1 = Wn + (size_t)(oB + r1) * DIN + c1 * 8;
    const int dA0 = s0 * 16, dA1 = s1 * 16;
    const int dB0 = BREG + s0 * 16, dB1 = BREG + s1 * 16;

    auto STAGE = [&](int bufB) {                  // 4 loads, advances K by 32
        load_lds_16B(gA0, sm + bufB + dA0);
        load_lds_16B(gA1, sm + bufB + dA1);
        load_lds_16B(gB0, sm + bufB + dB0);
        load_lds_16B(gB1, sm + bufB + dB1);
        gA0 += BK2; gA1 += BK2; gB0 += BK2; gB1 += BK2;
    };
    auto COMPUTE = [&](int bufB) {                // 12 ds_read_b128 + 32 MFMA
        const char* base = sm + bufB;
        bf16x8 af[8], bv[4];
        #pragma unroll
        for (int mi = 0; mi < 8; mi++)
            af[mi] = __builtin_bit_cast(bf16x8, *(const short8v*)(base + aOff[mi]));
        #pragma unroll
        for (int ni = 0; ni < 4; ni++)
            bv[ni] = __builtin_bit_cast(bf16x8, *(const short8v*)(base + bOff[ni]));
        __builtin_amdgcn_s_setprio(1);
        #pragma unroll
        for (int mi = 0; mi < 8; mi++)
            #pragma unroll
            for (int ni = 0; ni < 4; ni++)
                acc[mi][ni] = __builtin_amdgcn_mfma_f32_16x16x32_bf16(
                    af[mi], bv[ni], acc[mi][ni], 0, 0, 0);
        __builtin_amdgcn_s_setprio(0);
    };

    // prologue: stage steps 0,1; land step 0; enter loop with step 1 in flight
    STAGE(0);
    STAGE(BUFB);
    asm volatile("s_waitcnt vmcnt(4)" ::: "memory");
    __builtin_amdgcn_sched_barrier(0);
    __builtin_amdgcn_s_barrier();
    __builtin_amdgcn_sched_barrier(0);

    int cb = 0, sb = 2 * BUFB;
    #pragma unroll 1
    for (int t = 0; t < NSTEP2 - 2; ++t) {
        STAGE(sb);                                // step t+2
        COMPUTE(cb);                              // step t
        asm volatile("s_waitcnt vmcnt(4)" ::: "memory");  // step t+1 landed
        __builtin_amdgcn_sched_barrier(0);
        __builtin_amdgcn_s_barrier();
        __builtin_amdgcn_sched_barrier(0);
        cb = (cb == 2 * BUFB) ? 0 : cb + BUFB;
        sb = (sb == 2 * BUFB) ? 0 : sb + BUFB;
    }
    COMPUTE(0);                                   // step 30 (30%3==0)
    asm volatile("s_waitcnt vmcnt(0)" ::: "memory");      // step 31 landed
    __builtin_amdgcn_sched_barrier(0);
    __builtin_amdgcn_s_barrier();
    __builtin_amdgcn_sched_barrier(0);
    COMPUTE(BUFB);                                // step 31

    __syncthreads();                              // staging free; potS aliases

    // 4 chunks of 64 rows (= 1 sample each): acc -> potS (quad-XOR banks),
    // then 256-thread IF scan over T.
    float* potS = (float*)sm;                     // 64 x 256 fp32 = 64 KB
    #pragma unroll
    for (int s = 0; s < 4; ++s) {
        if (wr == (s >> 1)) {
            const int mib = (s & 1) * 4;
            #pragma unroll
            for (int m2 = 0; m2 < 4; ++m2)
                #pragma unroll
                for (int ni = 0; ni < 4; ++ni)
                    #pragma unroll
                    for (int r = 0; r < 4; ++r) {
                        int rl  = m2 * 16 + quad * 4 + r;
                        int col = (wc * 64 + ni * 16 + l15) ^ (quad << 3);
                        potS[rl * BN2 + col] = acc[mib + m2][ni][r];
                    }
        }
        __syncthreads();
        if (tid < BN2) {
            int n = bs * 4 + s;
            float pot = 0.f, cnt = 0.f;
            const float bst = bstepS[tid];
            float* so = out + (size_t)n * T * DOUT + oB + tid;
            for (int t = 0; t < T; t++) {
                pot += potS[t * BN2 + (tid ^ (((t >> 2) & 3) << 3))] + bst;
                float spk = (pot >= 1.0f) ? 1.0f : 0.0f;
                pot -= spk;
                cnt += spk;
                __builtin_nontemporal_store(spk, so + (size_t)t * DOUT);
            }
            __builtin_nontemporal_store(
                cnt, out + (size_t)NB * T * DOUT + (size_t)n * DOUT + oB + tid);
        }
        __syncthreads();
    }
}

// ===================== fallback (round-2 proven path) =====================

constexpr int BM = 128, BN = 128, BK = 64;
constexpr int LDA_F = 72;
constexpr int A_BYTES_F = BM * LDA_F * 2;
constexpr int SMEM_F = A_BYTES_F + BN * BK * 2;

template <bool PREFOLD>
__global__ void __launch_bounds__(256)
snn_gemm_if(const float* __restrict__ A, const float* __restrict__ W,
            const short* __restrict__ Wn,
            const float* __restrict__ bias, const float* __restrict__ gamma,
            const float* __restrict__ beta, const float* __restrict__ rmean,
            const float* __restrict__ rvar, float* __restrict__ out) {
    __shared__ __align__(16) char smem[SMEM_F];
    __shared__ float ratioS[BN];
    __shared__ float bstepS[BN];
    short* AsS  = (short*)smem;
    short* BsS  = (short*)(smem + A_BYTES_F);
    float* potS = (float*)smem;

    const int tid   = threadIdx.x;
    const int by    = blockIdx.y;
    const int oBase = blockIdx.x * BN;

    if (tid < BN) {
        int o = oBase + tid;
        float r = gamma[o] / sqrtf(rvar[o]);
        ratioS[tid] = r;
        bstepS[tid] = ((bias[o] - rmean[o]) * r + beta[o]) * (1.0f / 64.0f);
    }
    __syncthreads();

    const int lane = tid & 63;
    const int wv   = tid >> 6;
    const int wr   = wv & 1;
    const int wc   = wv >> 1;
    const int l15  = lane & 15;
    const int quad = lane >> 4;

    f32x4 acc[4][4] = {};
    const float* Ab = A + (size_t)by * BM * DIN;

    for (int kb = 0; kb < DIN; kb += BK) {
        float4v av[4][2];
        #pragma unroll
        for (int i = 0; i < 4; i++) {
            int g = i * 256 + tid;
            int r = g >> 3, k8 = g & 7;
            const float4v* p = (const float4v*)(Ab + (size_t)r * DIN + kb + k8 * 8);
            av[i][0] = p[0];
            av[i][1] = p[1];
        }
        float4v bv[4][2];
        if constexpr (!PREFOLD) {
            #pragma unroll
            for (int i = 0; i < 4; i++) {
                int slot = i * 256 + tid;
                int r = slot >> 3, k8 = (slot & 7) ^ (r & 7);
                const float4v* p = (const float4v*)(W + (size_t)(oBase + r) * DIN + kb + k8 * 8);
                bv[i][0] = p[0];
                bv[i][1] = p[1];
            }
        }
        __syncthreads();

        if constexpr (PREFOLD) {
            #pragma unroll
            for (int i = 0; i < 4; i++) {
                int slot = i * 256 + tid;
                int r = slot >> 3, k8 = (slot & 7) ^ (r & 7);
                load_lds_16B(Wn + (size_t)(oBase + r) * DIN + kb + k8 * 8,
                             BsS + (size_t)slot * 8);
            }
        } else {
            #pragma unroll
            for (int i = 0; i < 4; i++) {
                int slot = i * 256 + tid;
                int r = slot >> 3;
                float rt = ratioS[r];
                short8v s;
                #pragma unroll
                for (int j = 0; j < 4; j++) {
                    s[j]     = f2bf_rne(bv[i][0][j] * rt);
                    s[j + 4] = f2bf_rne(bv[i][1][j] * rt);
                }
                *(short8v*)(BsS + (size_t)slot * 8) = s;
            }
        }
        #pragma unroll
        for (int i = 0; i < 4; i++) {
            int g = i * 256 + tid;
            int r = g >> 3, k8 = g & 7;
            short8v s;
            #pragma unroll
            for (int j = 0; j < 4; j++) {
                s[j]     = f2bf_trunc(av[i][0][j]);
                s[j + 4] = f2bf_trunc(av[i][1][j]);
            }
            *(short8v*)(&AsS[r * LDA_F + k8 * 8]) = s;
        }
        __syncthreads();

        #pragma unroll
        for (int ks = 0; ks < 2; ks++) {
            bf16x8 af[4], bfv[4];
            #pragma unroll
            for (int mi = 0; mi < 4; mi++)
                af[mi] = __builtin_bit_cast(bf16x8,
                    *(const short8v*)(&AsS[(wr * 64 + mi * 16 + l15) * LDA_F + ks * 32 + quad * 8]));
            #pragma unroll
            for (int ni = 0; ni < 4; ni++) {
                int row  = wc * 64 + ni * 16 + l15;
                int slot = row * 8 + ((ks * 4 + quad) ^ (l15 & 7));
                bfv[ni] = __builtin_bit_cast(bf16x8, *(const short8v*)(BsS + (size_t)slot * 8));
            }
            #pragma unroll
            for (int mi = 0; mi < 4; mi++)
                #pragma unroll
                for (int ni = 0; ni < 4; ni++)
                    acc[mi][ni] = __builtin_amdgcn_mfma_f32_16x16x32_bf16(
                        af[mi], bfv[ni], acc[mi][ni], 0, 0, 0);
        }
    }

    __syncthreads();

    #pragma unroll 1
    for (int s = 0; s < 2; s++) {
        if (wr == s) {
            #pragma unroll
            for (int mi = 0; mi < 4; mi++)
                #pragma unroll
                for (int ni = 0; ni < 4; ni++)
                    #pragma unroll
                    for (int r = 0; r < 4; r++)
                        potS[(mi * 16 + quad * 4 + r) * BN + wc * 64 + ni * 16 + l15] =
                            acc[mi][ni][r];
        }
        __syncthreads();
        if (tid < BN) {
            int n = by * 2 + s;
            float pot = 0.f, cnt = 0.f;
            const float bst = bstepS[tid];
            float* so = out + (size_t)n * T * DOUT + oBase + tid;
            for (int t = 0; t < T; t++) {
                pot += potS[t * BN + tid] + bst;
                float spk = (pot >= 1.0f) ? 1.0f : 0.0f;
                pot -= spk;
                cnt += spk;
                so[(size_t)t * DOUT] = spk;
            }
            out[(size_t)NB * T * DOUT + (size_t)n * DOUT + oBase + tid] = cnt;
        }
        __syncthreads();
    }
}

extern "C" void kernel_launch(void* const* d_in, const int* in_sizes, int n_in,
                              void* d_out, int out_size, void* d_ws, size_t ws_size,
                              hipStream_t stream) {
    const float* A     = (const float*)d_in[0];
    // d_in[1] (input_features_sc) feeds only the un-returned ANN path — dead.
    const float* W     = (const float*)d_in[2];
    const float* bias  = (const float*)d_in[3];
    const float* gamma = (const float*)d_in[4];
    const float* beta  = (const float*)d_in[5];
    const float* rmean = (const float*)d_in[6];
    const float* rvar  = (const float*)d_in[7];
    float* out = (float*)d_out;

    if (d_ws != nullptr && ws_size >= WS_BF16) {
        short* Abf = (short*)d_ws;
        short* Wn  = (short*)((char*)d_ws + ABF_BYTES);
        prep_fused<<<PREP_A_BLOCKS + PREP_W_BLOCKS, 256, 0, stream>>>(
            A, Abf, W, gamma, rvar, Wn);
        dim3 grid(DOUT / BN2, NB / 4);   // (4, 128): col-blocks of one A panel adjacent
        snn_gemm_if_256<<<grid, 512, 0, stream>>>(Abf, Wn, bias, gamma, beta,
                                                  rmean, rvar, out);
    } else if (d_ws != nullptr && ws_size >= WN_BYTES) {
        short* Wn = (short*)d_ws;
        fold_w_kernel<<<DOUT * DIN / 4 / 256, 256, 0, stream>>>(W, gamma, rvar, Wn);
        dim3 grid(DOUT / BN, NB / 2);
        snn_gemm_if<true><<<grid, 256, 0, stream>>>(A, W, Wn, bias, gamma, beta,
                                                    rmean, rvar, out);
    } else {
        dim3 grid(DOUT / BN, NB / 2);
        snn_gemm_if<false><<<grid, 256, 0, stream>>>(A, W, nullptr, bias, gamma, beta,
                                                     rmean, rvar, out);
    }
}